// Round 10
// baseline (214.062 us; speedup 1.0000x reference)
//
#include <hip/hip_runtime.h>
#include <cmath>

// Temporal Contrast Enhancement — R13: segment-sequential single-read fusion,
// 512 threads. R9 post-mortem: single-read structure confirmed (FETCH 176->44
// MB, 99.6us) but now serial-latency-bound: 1 wave/SIMD, dep-chain recurrence
// (~8cyc/elem) with 64% idle. Fix: 512-thread blocks, CHT=512 -> NSEG 9->5:
// per-thread serial work HALVES (8.6->4.3 chunks) and 2 waves/SIMD co-issue
// through each other's dep stalls (compute phases between barriers are long,
// unlike R6's staging-paced lockstep). LDS 90KB -> still 1 block/CU;
// waves_per_eu(2,2) -> 256-VGPR budget (R9 used 132; no spill).

typedef float f32x4 __attribute__((ext_vector_type(4)));

static constexpr int   kT  = 88200;
static constexpr float kSR = 44100.0f;

static constexpr int S       = 40;                  // chunk length
static constexpr int NC      = kT / S;              // 2205 chunks/series
static constexpr int PADS    = S + 4;               // padded LDS chunk stride
static constexpr int FTH     = 512;                 // threads = chunks/segment
static constexpr int NSEG    = (NC + FTH - 1) / FTH;    // 5 segments
static constexpr int TAILC   = NC - FTH * (NSEG - 1);   // 157
static constexpr int F4C     = S / 4;               // 10 float4 per chunk
static constexpr int TILE_F4 = FTH * F4C;           // 5120 float4 per segment
static constexpr int TAIL_F4 = TAILC * F4C;         // 1570
static constexpr int BUF_F   = FTH * PADS;          // 22528 floats (90112 B)
static constexpr int NWAVE   = FTH / 64;            // 8

struct EnvP { float ad, bd, aa, ba, nuamp, reg; };

__device__ __forceinline__ EnvP make_params(const float* tauA, const float* tauD,
                                            const float* nu, const float* dbreg) {
  EnvP p;
  float td = fminf(fmaxf(tauD[0], 1.0f), 100.0f);
  td = fminf(fmaxf(td, 0.1f), 1000.0f) * 0.001f;
  float ta = fminf(fmaxf(tauA[0], 1.0f), 100.0f);
  ta = fminf(fmaxf(ta, 0.1f), 1000.0f) * 0.001f;
  p.ad = expf(-1.0f / (td * kSR));
  p.aa = expf(-1.0f / (ta * kSR));
  p.bd = 1.0f - p.ad;
  p.ba = 1.0f - p.aa;
  p.nuamp = exp10f(fminf(fmaxf(nu[0],    -60.0f),   0.0f) * 0.05f);
  p.reg   = exp10f(fminf(fmaxf(dbreg[0], -120.0f), -60.0f) * 0.05f);
  return p;
}

// Segment-level scan of chunk maps f(y) = op(A, G*y + B) with scalar carry.
// Returns this thread's chunk-init value; thread 0 updates the carry slot.
// wA/wB/wG: NWAVE-entry wave-total arrays (per mode; no cross-scan reuse).
// carry2: double-buffered {read [g&1], write [(g+1)&1]}.
template <int ATTACK>
__device__ __forceinline__ float seg_scan(float a, float b, bool valid,
                                          const float gS,
                                          volatile float* wA, volatile float* wB,
                                          volatile float* wG,
                                          float* carry2, int g, int t) {
  const float ID_A = ATTACK ? INFINITY : -INFINITY;
  float gg = gS;
  if (!valid) { a = ID_A; b = 0.0f; gg = 1.0f; }
  const int lane = t & 63, wid = t >> 6;
  // intra-wave inclusive scan (Hillis-Steele), no barriers
#pragma unroll
  for (int d = 1; d < 64; d <<= 1) {
    float pa = __shfl_up(a, d), pb = __shfl_up(b, d), pg = __shfl_up(gg, d);
    if (lane >= d) {
      float na = ATTACK ? fminf(a, fmaf(gg, pa, b)) : fmaxf(a, fmaf(gg, pa, b));
      b  = fmaf(gg, pb, b);
      gg = gg * pg;
      a  = na;
    }
  }
  if (lane == 63) { wA[wid] = a; wB[wid] = b; wG[wid] = gg; }
  __syncthreads();
  const float cin = carry2[g & 1];
  // wave prefix P = totals of waves [0, wid)
  float Pa = ID_A, Pb = 0.0f, Pg = 1.0f;
#pragma unroll
  for (int w = 0; w < NWAVE - 1; ++w) {
    if (w < wid) {
      float ca = wA[w], cb = wB[w], cg = wG[w];
      float na = ATTACK ? fminf(ca, fmaf(cg, Pa, cb)) : fmaxf(ca, fmaf(cg, Pa, cb));
      Pb = fmaf(cg, Pb, cb);
      Pg = cg * Pg;
      Pa = na;
    }
  }
  // exclusive-in-wave
  float xa = __shfl_up(a, 1), xb = __shfl_up(b, 1), xg = __shfl_up(gg, 1);
  if (lane == 0) { xa = ID_A; xb = 0.0f; xg = 1.0f; }
  // E = excl ∘ P  (map over chunks [segment start, this chunk))
  float Ea = ATTACK ? fminf(xa, fmaf(xg, Pa, xb)) : fmaxf(xa, fmaf(xg, Pa, xb));
  float Eb = fmaf(xg, Pb, xb);
  float Eg = xg * Pg;
  float init = ATTACK ? fminf(Ea, fmaf(Eg, cin, Eb)) : fmaxf(Ea, fmaf(Eg, cin, Eb));
  // segment-total map F -> carry' (written to the OTHER slot; no race)
  if (t == 0) {
    float Fa = ID_A, Fb = 0.0f, Fg = 1.0f;
#pragma unroll
    for (int w = 0; w < NWAVE; ++w) {
      float ca = wA[w], cb = wB[w], cg = wG[w];
      float na = ATTACK ? fminf(ca, fmaf(cg, Fa, cb)) : fmaxf(ca, fmaf(cg, Fa, cb));
      Fb = fmaf(cg, Fb, cb);
      Fg = cg * Fg;
      Fa = na;
    }
    carry2[(g + 1) & 1] = ATTACK ? fminf(Fa, fmaf(Fg, cin, Fb))
                                 : fmaxf(Fa, fmaf(Fg, cin, Fb));
  }
  return init;
}

#define REPEAT10(M) M(0) M(1) M(2) M(3) M(4) M(5) M(6) M(7) M(8) M(9)

// ---- the fused one-block-per-series kernel --------------------------------
// 90KB static LDS -> 1 block/CU -> 8 waves = 2/SIMD; waves_per_eu(2,2) gives
// a 256-VGPR budget so the 10 named prefetch regs + recurrence state stay
// resident (proven R5/R9 pattern, no scratch).
__global__
__attribute__((amdgpu_flat_work_group_size(512, 512), amdgpu_waves_per_eu(2, 2)))
void k_one(const float* __restrict__ x,
           const float* tauA, const float* tauD,
           const float* nu, const float* dbreg,
           float* __restrict__ out) {
  __shared__ float buf[BUF_F];                // 90112 B
  __shared__ float wAm[3][NWAVE], wBm[3][NWAVE], wGm[3][NWAVE];
  __shared__ float carry[3][2];               // [mode][g&1]
  const int t = threadIdx.x;
  const float* xs = x   + (size_t)blockIdx.x * kT;
  float*       os = out + (size_t)blockIdx.x * kT;
  EnvP p = make_params(tauA, tauD, nu, dbreg);
  const float gSd = powf(p.ad, (float)S);
  const float gSa = powf(p.aa, (float)S);

  if (t < 3) { carry[t][0] = 0.0f; carry[t][1] = 0.0f; }  // y0 = 0

  // 10 NAMED prefetch registers + 10 NAMED hoisted LDS addresses.
#define DECL_R(K) f32x4 r##K;
  REPEAT10(DECL_R)
#undef DECL_R
#define DECL_A(K) const int a##K = ((t + K * FTH) / F4C) * PADS \
                                   + ((t + K * FTH) % F4C) * 4;
  REPEAT10(DECL_A)
#undef DECL_A
  const f32x4* xg4 = reinterpret_cast<const f32x4*>(xs);

#define LD1(K) { int i_ = t + K * FTH; r##K = xg_[i_ < nf4_ ? i_ : 0]; }
#define LD_TILE(TILE)                                                        \
  do {                                                                       \
    const int nf4_ = ((TILE) == NSEG - 1) ? TAIL_F4 : TILE_F4;               \
    const f32x4* xg_ = xg4 + (size_t)(TILE) * TILE_F4;                       \
    REPEAT10(LD1)                                                            \
  } while (0)
#define WR1(K) *reinterpret_cast<f32x4*>(buf + a##K) = r##K;
#define WR_TILE() do { REPEAT10(WR1) } while (0)

  LD_TILE(0);
  WR_TILE();
  __syncthreads();                            // buf ready; carries visible

  for (int g = 0; g < NSEG; ++g) {
    const bool pf = (g + 1 < NSEG);
    if (pf) LD_TILE(g + 1);                   // issue next-segment loads NOW
    __builtin_amdgcn_sched_barrier(0);        // pin issue before compute

    const int  c     = g * FTH + t;
    const bool valid = c < NC;
    const float* my  = buf + t * PADS;
    float* myw       = buf + t * PADS;

    // ---- mode 0: decay env of |x| -> chunk map; scan -> ydI --------------
    float A = -INFINITY, B = 0.0f;
#pragma unroll
    for (int i = 0; i < F4C; ++i) {
      f32x4 v = *reinterpret_cast<const f32x4*>(my + 4 * i);
#pragma unroll
      for (int j = 0; j < 4; ++j) {
        float xa = fabsf(v[j]);
        float bx = p.bd * xa;
        A = fmaxf(xa, fmaf(p.ad, A, bx));
        B = fmaf(p.ad, B, bx);
      }
    }
    const float ydI = seg_scan<0>(A, B, valid, gSd, wAm[0], wBm[0], wGm[0],
                                  carry[0], g, t);

    // ---- mode 1: attack env of yd -> chunk map; scan -> yaI --------------
    {
      float yd = ydI;
      A = INFINITY; B = 0.0f;
#pragma unroll
      for (int i = 0; i < F4C; ++i) {
        f32x4 v = *reinterpret_cast<const f32x4*>(my + 4 * i);
#pragma unroll
        for (int j = 0; j < 4; ++j) {
          float xa = fabsf(v[j]);
          yd = fmaxf(xa, fmaf(p.ad, yd, p.bd * xa));
          float by = p.ba * yd;
          A = fminf(yd, fmaf(p.aa, A, by));
          B = fmaf(p.aa, B, by);
        }
      }
    }
    const float yaI = seg_scan<1>(A, B, valid, gSa, wAm[1], wBm[1], wGm[1],
                                  carry[1], g, t);

    // ---- mode 2: decay env of et -> chunk map; scan -> yeI ---------------
    {
      float yd = ydI, ya = yaI;
      A = -INFINITY; B = 0.0f;
#pragma unroll
      for (int i = 0; i < F4C; ++i) {
        f32x4 v = *reinterpret_cast<const f32x4*>(my + 4 * i);
#pragma unroll
        for (int j = 0; j < 4; ++j) {
          float xa = fabsf(v[j]);
          yd = fmaxf(xa, fmaf(p.ad, yd, p.bd * xa));
          ya = fminf(yd, fmaf(p.aa, ya, p.ba * yd));
          float et = fmaxf((yd - ya) - p.nuamp, 0.0f);
          float bx = p.bd * et;
          A = fmaxf(et, fmaf(p.ad, A, bx));
          B = fmaf(p.ad, B, bx);
        }
      }
    }
    const float yeI = seg_scan<0>(A, B, valid, gSd, wAm[2], wBm[2], wGm[2],
                                  carry[2], g, t);

    // ---- mode 3: final modulation, in-place into buf ---------------------
    {
      float yd = ydI, ya = yaI, ye = yeI;
#pragma unroll
      for (int i = 0; i < F4C; ++i) {
        f32x4 v = *reinterpret_cast<const f32x4*>(my + 4 * i);
        f32x4 oo;
#pragma unroll
        for (int j = 0; j < 4; ++j) {
          float xa = fabsf(v[j]);
          yd = fmaxf(xa, fmaf(p.ad, yd, p.bd * xa));
          ya = fminf(yd, fmaf(p.aa, ya, p.ba * yd));
          float et = fmaxf((yd - ya) - p.nuamp, 0.0f);
          ye = fmaxf(et, fmaf(p.ad, ye, p.bd * et));
          oo[j] = v[j] * (et / (ye + p.reg));
        }
        *reinterpret_cast<f32x4*>(myw + 4 * i) = oo;
      }
    }
    __syncthreads();                          // results visible for transpose

    // ---- coalesced nontemporal out-store (reads own aK slots) ------------
    {
      f32x4* og = reinterpret_cast<f32x4*>(os) + (size_t)g * TILE_F4;
      const int nf4o = pf ? TILE_F4 : TAIL_F4;
#define ST1(K) { int i_ = t + K * FTH;                                        \
                 if (i_ < nf4o)                                               \
                   __builtin_nontemporal_store(                               \
                     *reinterpret_cast<const f32x4*>(buf + a##K), &og[i_]); }
      REPEAT10(ST1)
#undef ST1
    }
    if (pf) WR_TILE();                        // own slots: read-then-write OK
    __syncthreads();                          // buf stable for next segment
  }
#undef LD1
#undef LD_TILE
#undef WR1
#undef WR_TILE
}

extern "C" void kernel_launch(void* const* d_in, const int* in_sizes, int n_in,
                              void* d_out, int out_size, void* d_ws, size_t ws_size,
                              hipStream_t stream) {
  const float* x     = (const float*)d_in[0];
  const float* tauA  = (const float*)d_in[1];
  const float* tauD  = (const float*)d_in[2];
  const float* nu    = (const float*)d_in[3];
  const float* dbreg = (const float*)d_in[4];
  float* out = (float*)d_out;
  const int nseries = in_sizes[0] / kT;       // 256
  (void)d_ws; (void)ws_size;                  // no workspace needed

  k_one<<<nseries, FTH, 0, stream>>>(x, tauA, tauD, nu, dbreg, out);
}